// Round 2
// baseline (368.400 us; speedup 1.0000x reference)
//
#include <hip/hip_runtime.h>

#define BLOCK 256

// s = 0.05, C = 64
// loss_row = A*(LSE*Wsum - sum_c w_c x_c) + Bc*w_t*(LSE - x_t)
//   A  = s/(C-1)
//   Bc = (1-s) - s/(C-1)

__global__ __launch_bounds__(BLOCK) void wlsce_kernel(
    const float* __restrict__ x,     // [nrows, 64] logits
    const int*   __restrict__ tgt,   // [nrows]
    const float* __restrict__ w,     // [64]
    float*       __restrict__ out,   // [1]
    int nrows, float inv_n)
{
    const int lane = threadIdx.x & 63;
    const int g    = lane >> 4;   // which of the 4 rows this wave handles
    const int gl   = lane & 15;   // lane within the 16-lane row group
    const int c0   = gl << 2;     // first of this lane's 4 classes

    // per-lane class weights (each 16-lane group covers all 64 classes)
    const float4 w4 = *reinterpret_cast<const float4*>(w + c0);
    float wsum = w4.x + w4.y + w4.z + w4.w;
    #pragma unroll
    for (int m = 1; m < 16; m <<= 1) wsum += __shfl_xor(wsum, m, 64);

    const float A  = 0.05f / 63.0f;
    const float Bc = (1.0f - 0.05f) - A;

    const int nwaves = (gridDim.x * BLOCK) >> 6;
    const int wid    = (blockIdx.x * BLOCK + threadIdx.x) >> 6;

    float acc = 0.0f;
    for (int r0 = wid * 4; r0 < nrows; r0 += nwaves * 4) {
        const int row = r0 + g;
        // wave loads rows [r0, r0+4): lane `l` gets floats [l*4, l*4+4) of that
        // 256-float span -> fully coalesced 1 KiB per wave
        const float4 xv =
            *reinterpret_cast<const float4*>(x + (size_t)r0 * 64 + (size_t)lane * 4);

        // row max (reduce over the 16-lane group)
        float mx = fmaxf(fmaxf(xv.x, xv.y), fmaxf(xv.z, xv.w));
        #pragma unroll
        for (int m = 1; m < 16; m <<= 1) mx = fmaxf(mx, __shfl_xor(mx, m, 64));

        // sum of exp(x - mx) and weighted dot, reduced together
        float se = __expf(xv.x - mx) + __expf(xv.y - mx) +
                   __expf(xv.z - mx) + __expf(xv.w - mx);
        float wd = w4.x * xv.x + w4.y * xv.y + w4.z * xv.z + w4.w * xv.w;
        #pragma unroll
        for (int m = 1; m < 16; m <<= 1) {
            se += __shfl_xor(se, m, 64);
            wd += __shfl_xor(wd, m, 64);
        }

        const float lse = mx + __logf(se);
        const int   t   = tgt[row];          // broadcast within group, L1/L2-hot
        const float wt  = w[t];              // broadcast, L1-hot

        // extract x_t in-register: lane g*16 + (t>>2) holds element (t&3)
        const float xsel = (t & 2) ? ((t & 1) ? xv.w : xv.z)
                                   : ((t & 1) ? xv.y : xv.x);
        const float xt = __shfl(xsel, (g << 4) | (t >> 2), 64);

        const float loss = A * (lse * wsum - wd) + Bc * wt * (lse - xt);
        if (gl == 0) acc += loss;   // one lane per row group accumulates
    }

    // wave-level sum of the 4 group lanes (0,16,32,48)
    acc += __shfl_xor(acc, 16, 64);
    acc += __shfl_xor(acc, 32, 64);

    __shared__ float red[BLOCK / 64];
    if (lane == 0) red[threadIdx.x >> 6] = acc;
    __syncthreads();
    if (threadIdx.x == 0) {
        float s = 0.0f;
        #pragma unroll
        for (int i = 0; i < BLOCK / 64; ++i) s += red[i];
        atomicAdd(out, s * inv_n);
    }
}

extern "C" void kernel_launch(void* const* d_in, const int* in_sizes, int n_in,
                              void* d_out, int out_size, void* d_ws, size_t ws_size,
                              hipStream_t stream) {
    const float* x   = (const float*)d_in[0];
    const int*   tgt = (const int*)d_in[1];
    const float* w   = (const float*)d_in[2];
    float*       out = (float*)d_out;

    const int nrows = in_sizes[0] / 64;  // B*D = 1,048,576 (divisible by 4)

    // d_out is re-poisoned to 0xAA before every timed launch
    hipMemsetAsync(out, 0, sizeof(float), stream);

    const int grid = 2048;
    wlsce_kernel<<<grid, BLOCK, 0, stream>>>(x, tgt, w, out, nrows,
                                             1.0f / (float)nrows);
}